// Round 12
// baseline (176.987 us; speedup 1.0000x reference)
//
#include <hip/hip_runtime.h>

// Problem constants: N=2048, L=4096, M=512, P=512
#define NN 2048
#define LL 4096
#define MM 512
#define PP 512

#define NBLOCKS 256
#define NTHREADS 512
#define SWEEPS 13              // tanh-Jacobi sweeps after eps0 = tanh(a/Lam)
#define RICH 10                // Richardson iterations for E x = b

typedef unsigned short ushort_t;
typedef unsigned int   uint_t;
typedef unsigned long long ull_t;

__device__ __forceinline__ float wave_reduce_sum(float v) {
#pragma unroll
    for (int off = 32; off > 0; off >>= 1) v += __shfl_xor(v, off, 64);
    return v;
}

__device__ __forceinline__ ushort_t f2bf(float f) {  // RNE float->bf16
    uint_t x = __float_as_uint(f);
    uint_t r = ((x >> 16) & 1u) + 0x7fffu;
    return (ushort_t)((x + r) >> 16);
}
__device__ __forceinline__ uint_t pack2(float lo, float hi) {
    return (uint_t)f2bf(lo) | ((uint_t)f2bf(hi) << 16);
}
__device__ __forceinline__ float bflo(uint_t w) { return __uint_as_float(w << 16); }
__device__ __forceinline__ float bfhi(uint_t w) { return __uint_as_float(w & 0xffff0000u); }
__device__ __forceinline__ int swz(int j) { return j ^ ((j >> 3) & 7); }

__device__ __forceinline__ uint4 cvt8(float4 f0, float4 f1) {
    uint4 o;
    o.x = pack2(f0.x, f0.y); o.y = pack2(f0.z, f0.w);
    o.z = pack2(f1.x, f1.y); o.w = pack2(f1.z, f1.w);
    return o;
}
__device__ __forceinline__ float dot8(uint4 w, float4 e0, float4 e1, float acc) {
    acc = fmaf(bflo(w.x), e0.x, acc); acc = fmaf(bfhi(w.x), e0.y, acc);
    acc = fmaf(bflo(w.y), e0.z, acc); acc = fmaf(bfhi(w.y), e0.w, acc);
    acc = fmaf(bflo(w.z), e1.x, acc); acc = fmaf(bfhi(w.z), e1.y, acc);
    acc = fmaf(bflo(w.w), e1.z, acc); acc = fmaf(bfhi(w.w), e1.w, acc);
    return acc;
}

// Tagged 8-byte publish: {float value (lo), int tag (hi)} in ONE relaxed
// agent-scope atomic — value and tag move atomically. Proven cross-XCD
// coherent (rounds 7/8/11).
__device__ __forceinline__ void tstore(float2* p, float v, int tag) {
    ull_t pk = (ull_t)__float_as_uint(v) | ((ull_t)(uint_t)tag << 32);
    __hip_atomic_store((ull_t*)p, pk, __ATOMIC_RELAXED, __HIP_MEMORY_SCOPE_AGENT);
}

// Stage a tagged vector (NENT entries) into LDS (values only, swizzled).
// Each thread polls its K = NENT/512 interleaved entries until all carry
// tag >= want. Determinism: a producer publishes tag s+1 only after fully
// consuming tag s, so no entry can be overwritten while still being awaited.
template<int NENT>
__device__ __forceinline__ void stage_vec(const float2* buf, int want,
                                          float* ev, int tid) {
    constexpr int K = NENT / 512;
    const ull_t* p = reinterpret_cast<const ull_t*>(buf);
    ull_t u[K];
    for (;;) {
        int tmin = 0x7fffffff;
#pragma unroll
        for (int k = 0; k < K; ++k) {
            u[k] = __hip_atomic_load(p + tid + k * 512, __ATOMIC_RELAXED,
                                     __HIP_MEMORY_SCOPE_AGENT);
            tmin = min(tmin, (int)(u[k] >> 32));
        }
        if (tmin >= want) break;
        __builtin_amdgcn_s_sleep(1);
    }
#pragma unroll
    for (int k = 0; k < K; ++k) {
        int e = tid + k * 512;                      // entry index
        ev[(swz(e >> 2) << 2) | (e & 3)] = __uint_as_float((uint_t)u[k]);
    }
}

// Batched fp32 row-dots: all loads issued before FMAs (ILP = 8 / 2).
__device__ __forceinline__ float dotN2048(const float* __restrict__ Mrow,
                                          const float4 (&xr)[8], int lane) {
    const float4* Mr = reinterpret_cast<const float4*>(Mrow);
    float4 m[8];
#pragma unroll
    for (int k = 0; k < 8; ++k) m[k] = Mr[lane + 64 * k];
    float acc = 0.f;
#pragma unroll
    for (int k = 0; k < 8; ++k) {
        acc = fmaf(m[k].x, xr[k].x, acc); acc = fmaf(m[k].y, xr[k].y, acc);
        acc = fmaf(m[k].z, xr[k].z, acc); acc = fmaf(m[k].w, xr[k].w, acc);
    }
    return acc;
}
__device__ __forceinline__ float dotM512(const float* __restrict__ Mrow,
                                         const float4 (&ur)[2], int lane) {
    const float4* Mr = reinterpret_cast<const float4*>(Mrow);
    float4 m[2];
#pragma unroll
    for (int k = 0; k < 2; ++k) m[k] = Mr[lane + 64 * k];
    float acc = 0.f;
#pragma unroll
    for (int k = 0; k < 2; ++k) {
        acc = fmaf(m[k].x, ur[k].x, acc); acc = fmaf(m[k].y, ur[k].y, acc);
        acc = fmaf(m[k].z, ur[k].z, acc); acc = fmaf(m[k].w, ur[k].w, acc);
    }
    return acc;
}

struct KArgs {
    const float *x, *u, *C1, *D11, *D12, *Lam, *F, *B1, *B2, *E, *C2, *D21, *D22;
    const float *bv, *bx, *bu;
    const int* t;
    float* yout; float* xout;
    float2 *epsA, *epsB, *bT, *xaT, *xbT;   // tagged vectors
};

// Clears all tagged buffers (14336 x 8B) every call — graph-replay safe.
__global__ __launch_bounds__(512) void clear_tags(ull_t* p) {
    p[blockIdx.x * 512 + threadIdx.x] = 0ull;
}

__global__ __launch_bounds__(NTHREADS, 2) void fused_kernel(KArgs A) {
    const int tid  = threadIdx.x;
    const int lane = tid & 63;
    const int warp = tid >> 6;
    const int W    = blockIdx.x * 8 + warp;        // 0..2047
    const int rowA = W;                             // short D11 row
    const int rowB = (LL - 1) - W;                  // long row; lenA+lenB=4095

    __shared__ float4 evec[1024];                   // 16 KB value staging
    float* ev = reinterpret_cast<float*>(evec);

    const float decay = __powf(0.95f, (float)(*A.t));

    // ---- x, u into registers (reused by all phase-A dots) -----------------
    float4 xr[8], ur[2];
    {
        const float4* Xv = reinterpret_cast<const float4*>(A.x);
        const float4* Uv = reinterpret_cast<const float4*>(A.u);
#pragma unroll
        for (int k = 0; k < 8; ++k) xr[k] = Xv[lane + 64 * k];
#pragma unroll
        for (int k = 0; k < 2; ++k) ur[k] = Uv[lane + 64 * k];
    }

    // ---- Phase A1: a-rows (critical path — publish eps0 ASAP) -------------
    float aA, lamA, aB, lamB;
    {
        float acc = dotN2048(A.C1 + (size_t)rowA * NN, xr, lane)
                  + dotM512(A.D12 + (size_t)rowA * MM, ur, lane);
        acc = wave_reduce_sum(acc);
        lamA = A.Lam[rowA];
        aA = fmaf(decay, A.bv[rowA], acc);
        if (lane == 0) tstore(&A.epsA[rowA], tanhf(aA / lamA), 1);

        acc = dotN2048(A.C1 + (size_t)rowB * NN, xr, lane)
            + dotM512(A.D12 + (size_t)rowB * MM, ur, lane);
        acc = wave_reduce_sum(acc);
        lamB = A.Lam[rowB];
        aB = fmaf(decay, A.bv[rowB], acc);
        if (lane == 0) tstore(&A.epsA[rowB], tanhf(aB / lamB), 1);
    }

    // ---- Phase A2: q, y0 (stay in registers) ------------------------------
    float q_r, y0_r = 0.f;
    {
        float acc = dotN2048(A.F + (size_t)W * NN, xr, lane)
                  + dotM512(A.B2 + (size_t)W * MM, ur, lane);
        acc = wave_reduce_sum(acc);
        q_r = fmaf(decay, A.bx[W], acc);
    }
    if (W < PP) {
        float acc = dotN2048(A.C2 + (size_t)W * NN, xr, lane)
                  + dotM512(A.D22 + (size_t)W * MM, ur, lane);
        acc = wave_reduce_sum(acc);
        y0_r = fmaf(decay, A.bu[W], acc);
    }

    // ---- Phase A3: matrix conversions into registers (batched loads) ------
    // D11 strict-tril zeros in memory make full-row loads exact: no guards.
    uint4 ra[4], rb[8], gr[4], rb1[8], rd21[8];
    {
        const float4* DrA = reinterpret_cast<const float4*>(A.D11 + (size_t)rowA * LL);
        float4 f[8];
#pragma unroll
        for (int kk = 0; kk < 4; ++kk) {
            f[2 * kk]     = DrA[128 * kk + 2 * lane];
            f[2 * kk + 1] = DrA[128 * kk + 2 * lane + 1];
        }
#pragma unroll
        for (int kk = 0; kk < 4; ++kk) ra[kk] = cvt8(f[2 * kk], f[2 * kk + 1]);
    }
    {
        const float4* DrB = reinterpret_cast<const float4*>(A.D11 + (size_t)rowB * LL);
        float4 f[16];
#pragma unroll
        for (int kk = 0; kk < 8; ++kk) {
            f[2 * kk]     = DrB[128 * kk + 2 * lane];
            f[2 * kk + 1] = DrB[128 * kk + 2 * lane + 1];
        }
#pragma unroll
        for (int kk = 0; kk < 8; ++kk) rb[kk] = cvt8(f[2 * kk], f[2 * kk + 1]);
    }
    {   // G = I - E, row W -> bf16 regs
        const float4* Er = reinterpret_cast<const float4*>(A.E + (size_t)W * NN);
        float4 f[8];
#pragma unroll
        for (int kk = 0; kk < 4; ++kk) {
            f[2 * kk]     = Er[128 * kk + 2 * lane];
            f[2 * kk + 1] = Er[128 * kk + 2 * lane + 1];
        }
#pragma unroll
        for (int kk = 0; kk < 4; ++kk) {
            int g0 = 8 * (kk * 64 + lane);
            float e[8] = {f[2*kk].x, f[2*kk].y, f[2*kk].z, f[2*kk].w,
                          f[2*kk+1].x, f[2*kk+1].y, f[2*kk+1].z, f[2*kk+1].w};
            uint_t wd[4];
#pragma unroll
            for (int j2 = 0; j2 < 4; ++j2) {
                float glo = ((g0 + 2 * j2)     == W ? 1.f : 0.f) - e[2 * j2];
                float ghi = ((g0 + 2 * j2 + 1) == W ? 1.f : 0.f) - e[2 * j2 + 1];
                wd[j2] = pack2(glo, ghi);
            }
            gr[kk] = make_uint4(wd[0], wd[1], wd[2], wd[3]);
        }
    }
    {   // B1 row W (4096 cols) -> bf16 regs
        const float4* Bv = reinterpret_cast<const float4*>(A.B1 + (size_t)W * LL);
        float4 f[16];
#pragma unroll
        for (int kk = 0; kk < 8; ++kk) {
            f[2 * kk]     = Bv[128 * kk + 2 * lane];
            f[2 * kk + 1] = Bv[128 * kk + 2 * lane + 1];
        }
#pragma unroll
        for (int kk = 0; kk < 8; ++kk) rb1[kk] = cvt8(f[2 * kk], f[2 * kk + 1]);
    }
    if (W < PP) {   // D21 row W (4096 cols) -> bf16 regs (uniform branch)
        const float4* Dv = reinterpret_cast<const float4*>(A.D21 + (size_t)W * LL);
        float4 f[16];
#pragma unroll
        for (int kk = 0; kk < 8; ++kk) {
            f[2 * kk]     = Dv[128 * kk + 2 * lane];
            f[2 * kk + 1] = Dv[128 * kk + 2 * lane + 1];
        }
#pragma unroll
        for (int kk = 0; kk < 8; ++kk) rd21[kk] = cvt8(f[2 * kk], f[2 * kk + 1]);
    } else {
#pragma unroll
        for (int kk = 0; kk < 8; ++kk) rd21[kk] = make_uint4(0u, 0u, 0u, 0u);
    }

    // ---- Phase B: tanh-Jacobi sweeps — tagged dataflow, no barriers -------
    for (int s = 1; s <= SWEEPS; ++s) {
        const float2* in = (s & 1) ? A.epsA : A.epsB;
        float2*      out = (s & 1) ? A.epsB : A.epsA;
        stage_vec<LL>(in, s, ev, tid);
        __syncthreads();
        float sA = 0.f, sB = 0.f;
#pragma unroll
        for (int kk = 0; kk < 4; ++kk) {
            int c = kk * 64 + lane;
            float4 e0 = evec[swz(2 * c)], e1 = evec[swz(2 * c + 1)];
            sA = dot8(ra[kk], e0, e1, sA);
            sB = dot8(rb[kk], e0, e1, sB);
        }
#pragma unroll
        for (int kk = 4; kk < 8; ++kk) {
            int c = kk * 64 + lane;
            float4 e0 = evec[swz(2 * c)], e1 = evec[swz(2 * c + 1)];
            sB = dot8(rb[kk], e0, e1, sB);
        }
        sA = wave_reduce_sum(sA);
        sB = wave_reduce_sum(sB);
        if (lane == 0) {
            tstore(&out[rowA], tanhf((aA + sA) / lamA), s + 1);
            tstore(&out[rowB], tanhf((aB + sB) / lamB), s + 1);
        }
        __syncthreads();   // LDS safe to overwrite next sweep
    }

    // ---- Phase C: y = D21 eps + y0 ; b = B1 eps + q (register dots) -------
    float b_r;
    {
        const float2* efin = (SWEEPS & 1) ? A.epsB : A.epsA;  // tag SWEEPS+1
        stage_vec<LL>(efin, SWEEPS + 1, ev, tid);
        __syncthreads();
        float accb = 0.f;
#pragma unroll
        for (int kk = 0; kk < 8; ++kk) {
            int c = kk * 64 + lane;
            float4 e0 = evec[swz(2 * c)], e1 = evec[swz(2 * c + 1)];
            accb = dot8(rb1[kk], e0, e1, accb);
        }
        accb = wave_reduce_sum(accb);
        b_r = q_r + accb;
        if (lane == 0) tstore(&A.bT[W], b_r, 1);
        if (W < PP) {
            float accy = 0.f;
#pragma unroll
            for (int kk = 0; kk < 8; ++kk) {
                int c = kk * 64 + lane;
                float4 e0 = evec[swz(2 * c)], e1 = evec[swz(2 * c + 1)];
                accy = dot8(rd21[kk], e0, e1, accy);
            }
            accy = wave_reduce_sum(accy);
            if (lane == 0) A.yout[W] = y0_r + accy;
        }
        __syncthreads();
    }

    // ---- Phase D: Richardson x <- b + G x, dataflow -------------------------
    {
        float2* buf[2] = { A.xaT, A.xbT };
        for (int k = 0; k < RICH; ++k) {
            const float2* xin = (k == 0) ? A.bT : buf[(k - 1) & 1];
            stage_vec<NN>(xin, k + 1, ev, tid);
            __syncthreads();
            float acc = 0.f;
#pragma unroll
            for (int kk = 0; kk < 4; ++kk) {
                int c = kk * 64 + lane;
                float4 e0 = evec[swz(2 * c)], e1 = evec[swz(2 * c + 1)];
                acc = dot8(gr[kk], e0, e1, acc);
            }
            acc = wave_reduce_sum(acc);
            float val = b_r + acc;
            if (lane == 0) {
                if (k == RICH - 1) A.xout[W] = val;           // final: plain store
                else tstore(&buf[k & 1][W], val, k + 2);
            }
            __syncthreads();
        }
    }
}

extern "C" void kernel_launch(void* const* d_in, const int* in_sizes, int n_in,
                              void* d_out, int out_size, void* d_ws, size_t ws_size,
                              hipStream_t stream) {
    KArgs A;
    A.x   = (const float*)d_in[0];
    A.u   = (const float*)d_in[1];
    A.C1  = (const float*)d_in[2];
    A.D11 = (const float*)d_in[3];
    A.D12 = (const float*)d_in[4];
    A.Lam = (const float*)d_in[5];
    A.F   = (const float*)d_in[6];
    A.B1  = (const float*)d_in[7];
    A.B2  = (const float*)d_in[8];
    A.E   = (const float*)d_in[9];
    A.C2  = (const float*)d_in[10];
    A.D21 = (const float*)d_in[11];
    A.D22 = (const float*)d_in[12];
    A.bv  = (const float*)d_in[13];
    A.bx  = (const float*)d_in[14];
    A.bu  = (const float*)d_in[15];
    A.t   = (const int*)d_in[16];
    A.yout = (float*)d_out;
    A.xout = (float*)d_out + PP;

    // Tagged buffers, contiguous from ws start: 14336 x 8B = 114,688 bytes
    float2* f2 = (float2*)d_ws;
    A.epsA = f2;            // 4096
    A.epsB = f2 + 4096;     // 4096
    A.bT   = f2 + 8192;     // 2048
    A.xaT  = f2 + 10240;    // 2048
    A.xbT  = f2 + 12288;    // 2048  (total 14336)

    clear_tags<<<28, 512, 0, stream>>>((ull_t*)d_ws);   // 28*512 = 14336

    void* params[] = { &A };
    hipLaunchCooperativeKernel((const void*)fused_kernel, dim3(NBLOCKS),
                               dim3(NTHREADS), params, 0, stream);
}